// Round 8
// baseline (315.955 us; speedup 1.0000x reference)
//
#include <hip/hip_runtime.h>

#define NN 100000
#define NE 1200000
#define NG 512
#define NSEG (3 * NN)
#define CHUNK 1024
#define NCHUNK ((NSEG + CHUNK - 1) / CHUNK)

typedef __bf16 bf16x8 __attribute__((ext_vector_type(8)));
typedef float f32x4 __attribute__((ext_vector_type(4)));

// ---- workspace layout (bytes), all 16B-aligned ----
static constexpr size_t AGG_OFF   = 0;                                  // 3*NN*64 f32
static constexpr size_t AGG_BYTES = (size_t)NSEG * 64 * 4;              // 76,800,000
static constexpr size_t CUR_OFF   = AGG_OFF + AGG_BYTES;                // NSEG ints (hist -> cursor)
static constexpr size_t START_OFF = CUR_OFF + (size_t)NSEG * 4;         // NSEG ints
static constexpr size_t CSUM_OFF  = START_OFF + (size_t)NSEG * 4;       // NCHUNK ints
static constexpr size_t ESRC_OFF  = CSUM_OFF + 4096;                    // NE ints (packed src|cb<<17)
static constexpr size_t POOL_OFF  = ESRC_OFF + (size_t)NE * 4;          // NG*64 f32
static constexpr size_t H0_OFF    = POOL_OFF + (size_t)NG * 64 * 4;     // NN*32 f32
static constexpr size_t H1_OFF    = H0_OFF + (size_t)NN * 32 * 4;       // NN*64 f32
static constexpr size_t H2_OFF    = H1_OFF + (size_t)NN * 64 * 4;       // NN*64 f32
static constexpr size_t WT1H_OFF  = H2_OFF + (size_t)NN * 64 * 4;       // 64*128 bf16
static constexpr size_t WT1L_OFF  = WT1H_OFF + 64 * 128 * 2;
static constexpr size_t WT2H_OFF  = WT1L_OFF + 64 * 128 * 2;            // 64*256 bf16
static constexpr size_t WT2L_OFF  = WT2H_OFF + 64 * 256 * 2;
static constexpr size_t TAB_OFF   = WT2L_OFF + 64 * 256 * 2;            // 256*32 f32 (32KB)
static constexpr size_t CB_OFF    = TAB_OFF + 256 * 32 * 4;             // NN bytes

// async global->LDS, 16B per lane; LDS dest = wave-uniform base + lane*16
__device__ __forceinline__ void async_copy16(void* lds, const void* g) {
    __builtin_amdgcn_global_load_lds(
        (const __attribute__((address_space(1))) void*)g,
        (__attribute__((address_space(3))) void*)lds, 16, 0, 0);
}

// ---- combo table: table[combo][32] = relu(concat(se[s],ce[c]) @ pre_w + pre_b)
__global__ __launch_bounds__(256)
void k_cbtable(const float* __restrict__ se, const float* __restrict__ ce,
               const float* __restrict__ pw, const float* __restrict__ pb,
               float* __restrict__ table) {
    __shared__ float sW[16 * 32];
    __shared__ float sB[32];
    for (int i = threadIdx.x; i < 512; i += 256) sW[i] = pw[i];
    if (threadIdx.x < 32) sB[threadIdx.x] = pb[threadIdx.x];
    __syncthreads();
    int cmb = threadIdx.x;            // 0..255
    int s = cmb >> 4, c = cmb & 15;
    float in[16];
#pragma unroll
    for (int k = 0; k < 8; k++) in[k] = se[s * 8 + k];
#pragma unroll
    for (int k = 0; k < 8; k++) in[8 + k] = ce[c * 8 + k];
    float acc[32];
#pragma unroll
    for (int j = 0; j < 32; j++) acc[j] = sB[j];
#pragma unroll
    for (int k = 0; k < 16; k++) {
        float hv = in[k];
#pragma unroll
        for (int j = 0; j < 32; j++) acc[j] += hv * sW[k * 32 + j];
    }
    float* o = table + (size_t)cmb * 32;
#pragma unroll
    for (int j = 0; j < 32; j += 4)
        *(float4*)(o + j) = make_float4(fmaxf(acc[j], 0.f), fmaxf(acc[j + 1], 0.f),
                                        fmaxf(acc[j + 2], 0.f), fmaxf(acc[j + 3], 0.f));
}

// ---- per-node init: cb[n] = combo id; h0[n][32] = table[cb[n]]
__global__ __launch_bounds__(256)
void k_node_init(const int* __restrict__ x, const float* __restrict__ table,
                 unsigned char* __restrict__ cb, float* __restrict__ h0) {
    int n = blockIdx.x * 256 + threadIdx.x;
    if (n >= NN) return;
    int si = x[2 * n], ci = x[2 * n + 1];
    int cmb = si * 16 + ci;
    cb[n] = (unsigned char)cmb;
    const float* t = table + (size_t)cmb * 32;
    float* o = h0 + (size_t)n * 32;
#pragma unroll
    for (int j = 0; j < 32; j += 4) *(float4*)(o + j) = *(const float4*)(t + j);
}

// ---- weight prep: Wt_hi/lo[j][k] (bf16, transposed, split) from [root | W_r] (fp32 [K][64])
__global__ __launch_bounds__(256)
void k_prepw(const float* __restrict__ root, const float* __restrict__ w,
             __bf16* __restrict__ wh, __bf16* __restrict__ wl, int cin) {
    int kt = 4 * cin;
    int t = blockIdx.x * 256 + threadIdx.x;
    if (t >= 64 * kt) return;
    int j = t / kt, k = t % kt;
    int sidx = k / cin, kk = k % cin;
    float v = (sidx == 0) ? root[kk * 64 + j]
                          : w[((size_t)(sidx - 1) * cin + kk) * 64 + j];
    __bf16 h = (__bf16)v;
    wh[t] = h;
    wl[t] = (__bf16)(v - (float)h);
}

// ---- histogram per (rel,dst) segment, 4 edges/thread
__global__ __launch_bounds__(256)
void k_count(const int* __restrict__ ei, const int* __restrict__ et, int* __restrict__ hist) {
    int e0 = (blockIdx.x * 256 + threadIdx.x) * 4;
    if (e0 >= NE) return;
    int4 d4 = *(const int4*)(ei + NE + e0);
    int4 t4 = *(const int4*)(et + e0);
    atomicAdd(&hist[t4.x * NN + d4.x], 1);
    atomicAdd(&hist[t4.y * NN + d4.y], 1);
    atomicAdd(&hist[t4.z * NN + d4.z], 1);
    atomicAdd(&hist[t4.w * NN + d4.w], 1);
}

// ---- scan pass 1: per-chunk sums
__global__ __launch_bounds__(256)
void k_chunksum(const int* __restrict__ hist, int* __restrict__ csum) {
    __shared__ int s[256];
    int b = blockIdx.x, t = threadIdx.x;
    int base = b * CHUNK + t * 4;
    int sum = 0;
#pragma unroll
    for (int k = 0; k < 4; k++) {
        int i = base + k;
        if (i < NSEG) sum += hist[i];
    }
    s[t] = sum;
    __syncthreads();
    for (int off = 128; off > 0; off >>= 1) {
        if (t < off) s[t] += s[t + off];
        __syncthreads();
    }
    if (t == 0) csum[b] = s[0];
}

// ---- scan pass 2: exclusive scan of chunk sums (one 512-thread block)
__global__ __launch_bounds__(512)
void k_chunkscan(int* __restrict__ csum) {
    __shared__ int s[512];
    int t = threadIdx.x;
    int v = (t < NCHUNK) ? csum[t] : 0;
    s[t] = v;
    __syncthreads();
    for (int off = 1; off < 512; off <<= 1) {
        int x = (t >= off) ? s[t - off] : 0;
        __syncthreads();
        s[t] += x;
        __syncthreads();
    }
    if (t < NCHUNK) csum[t] = s[t] - v;   // exclusive
}

// ---- scan pass 3: local exclusive scan; writes start[] and re-inits cur[] (cursor)
__global__ __launch_bounds__(256)
void k_localscan(int* __restrict__ hist_cur, const int* __restrict__ csum,
                 int* __restrict__ start) {
    __shared__ int s[256];
    int b = blockIdx.x, t = threadIdx.x;
    int base = b * CHUNK + t * 4;
    int v[4];
    int s4 = 0;
#pragma unroll
    for (int k = 0; k < 4; k++) {
        int i = base + k;
        v[k] = (i < NSEG) ? hist_cur[i] : 0;
        s4 += v[k];
    }
    s[t] = s4;
    __syncthreads();
    for (int off = 1; off < 256; off <<= 1) {
        int x = (t >= off) ? s[t - off] : 0;
        __syncthreads();
        s[t] += x;
        __syncthreads();
    }
    int excl = s[t] - s4 + csum[b];
#pragma unroll
    for (int k = 0; k < 4; k++) {
        int i = base + k;
        if (i < NSEG) {
            start[i] = excl;
            hist_cur[i] = excl;  // cursor for fill
        }
        excl += v[k];
    }
}

// ---- fill CSR edge array: esrc[pos] = src | (cb[src]<<17); 4 edges/thread
__global__ __launch_bounds__(256)
void k_fill(const int* __restrict__ ei, const int* __restrict__ et,
            const unsigned char* __restrict__ cb,
            int* __restrict__ cur, int* __restrict__ esrc) {
    int e0 = (blockIdx.x * 256 + threadIdx.x) * 4;
    if (e0 >= NE) return;
    int4 s4 = *(const int4*)(ei + e0);
    int4 d4 = *(const int4*)(ei + NE + e0);
    int4 t4 = *(const int4*)(et + e0);
    int c0 = cb[s4.x], c1 = cb[s4.y], c2 = cb[s4.z], c3 = cb[s4.w];
    int p0 = atomicAdd(&cur[t4.x * NN + d4.x], 1);
    int p1 = atomicAdd(&cur[t4.y * NN + d4.y], 1);
    int p2 = atomicAdd(&cur[t4.z * NN + d4.z], 1);
    int p3 = atomicAdd(&cur[t4.w * NN + d4.w], 1);
    esrc[p0] = s4.x | (c0 << 17);
    esrc[p1] = s4.y | (c1 << 17);
    esrc[p2] = s4.z | (c2 << 17);
    esrc[p3] = s4.w | (c3 << 17);
}

// ---- layer-1 gather from 256-row combo table (L1/L2-resident)
__global__ __launch_bounds__(256)
void k_gather_t(const int* __restrict__ start, const int* __restrict__ cur,
                const int* __restrict__ esrc, const float* __restrict__ table,
                float* __restrict__ agg) {
    int tid = blockIdx.x * 256 + threadIdx.x;
    int seg = tid >> 3;
    int p = tid & 7;
    if (seg >= NSEG) return;
    int st = start[seg], en = cur[seg];
    float4 acc = make_float4(0.f, 0.f, 0.f, 0.f);
    int i = st;
    for (; i + 4 <= en; i += 4) {
        int v0 = esrc[i], v1 = esrc[i + 1], v2 = esrc[i + 2], v3 = esrc[i + 3];
        float4 a = *(const float4*)(table + ((v0 >> 17) & 0xFF) * 32 + p * 4);
        float4 b = *(const float4*)(table + ((v1 >> 17) & 0xFF) * 32 + p * 4);
        float4 c = *(const float4*)(table + ((v2 >> 17) & 0xFF) * 32 + p * 4);
        float4 d = *(const float4*)(table + ((v3 >> 17) & 0xFF) * 32 + p * 4);
        acc.x += (a.x + b.x) + (c.x + d.x);
        acc.y += (a.y + b.y) + (c.y + d.y);
        acc.z += (a.z + b.z) + (c.z + d.z);
        acc.w += (a.w + b.w) + (c.w + d.w);
    }
    for (; i < en; i++) {
        int v = esrc[i];
        float4 a = *(const float4*)(table + ((v >> 17) & 0xFF) * 32 + p * 4);
        acc.x += a.x; acc.y += a.y; acc.z += a.z; acc.w += a.w;
    }
    int c = en - st;
    float inv = 1.f / (float)(c > 1 ? c : 1);
    acc.x *= inv; acc.y *= inv; acc.z *= inv; acc.w *= inv;
    *(float4*)(agg + (size_t)seg * 32 + p * 4) = acc;
}

// ---- layer-2 gather: agg[seg][0:64] = MEAN h[src][0:64]
__global__ __launch_bounds__(256)
void k_gather64(const int* __restrict__ start, const int* __restrict__ cur,
                const int* __restrict__ esrc, const float* __restrict__ h,
                float* __restrict__ agg) {
    int tid = blockIdx.x * 256 + threadIdx.x;
    int seg = tid >> 4;
    int p = tid & 15;
    if (seg >= NSEG) return;
    int st = start[seg], en = cur[seg];
    float4 acc = make_float4(0.f, 0.f, 0.f, 0.f);
    int i = st;
    for (; i + 4 <= en; i += 4) {
        int s0 = esrc[i] & 0x1FFFF, s1 = esrc[i + 1] & 0x1FFFF;
        int s2 = esrc[i + 2] & 0x1FFFF, s3 = esrc[i + 3] & 0x1FFFF;
        float4 v0 = *(const float4*)(h + (size_t)s0 * 64 + p * 4);
        float4 v1 = *(const float4*)(h + (size_t)s1 * 64 + p * 4);
        float4 v2 = *(const float4*)(h + (size_t)s2 * 64 + p * 4);
        float4 v3 = *(const float4*)(h + (size_t)s3 * 64 + p * 4);
        acc.x += (v0.x + v1.x) + (v2.x + v3.x);
        acc.y += (v0.y + v1.y) + (v2.y + v3.y);
        acc.z += (v0.z + v1.z) + (v2.z + v3.z);
        acc.w += (v0.w + v1.w) + (v2.w + v3.w);
    }
    for (; i < en; i++) {
        int s = esrc[i] & 0x1FFFF;
        float4 v = *(const float4*)(h + (size_t)s * 64 + p * 4);
        acc.x += v.x; acc.y += v.y; acc.z += v.z; acc.w += v.w;
    }
    int c = en - st;
    float inv = 1.f / (float)(c > 1 ? c : 1);
    acc.x *= inv; acc.y *= inv; acc.z *= inv; acc.w *= inv;
    *(float4*)(agg + (size_t)seg * 64 + p * 4) = acc;
}

// split 8 fp32 -> hi/lo bf16x8 fragments (hi+lo represents x to ~2^-18 rel)
__device__ __forceinline__ void split8(float4 a0, float4 a1, bf16x8& hi, bf16x8& lo) {
    float v[8] = {a0.x, a0.y, a0.z, a0.w, a1.x, a1.y, a1.z, a1.w};
#pragma unroll
    for (int i = 0; i < 8; i++) {
        __bf16 h = (__bf16)v[i];
        hi[i] = h;
        lo[i] = (__bf16)(v[i] - (float)h);
    }
}

// ---- combine via split-bf16 MFMA (unchanged from R7)
template <int CIN>
__global__ __launch_bounds__(256, 1)
void k_combine_m(const float* __restrict__ h_in, const float* __restrict__ agg,
                 const __bf16* __restrict__ wh, const __bf16* __restrict__ wl,
                 const float* __restrict__ bias, float* __restrict__ h_out) {
    constexpr int KT = 4 * CIN;          // 128 or 256
    constexpr int NCHK = KT / 64;        // 2 or 4 chunks of K=64
    __shared__ float sIN[64 * 64];       // 16 KB
    __shared__ __bf16 sWH[64 * 64];      // 8 KB
    __shared__ __bf16 sWL[64 * 64];      // 8 KB

    const int tid = threadIdx.x;
    const int wave = tid >> 6;
    const int lane = tid & 63;
    const int cA = lane & 15;
    const int kg = lane >> 4;
    const int n0 = blockIdx.x * 64;

    f32x4 acc[4];
#pragma unroll
    for (int nb = 0; nb < 4; nb++) {
        float bv = bias[nb * 16 + cA];
        acc[nb][0] = bv; acc[nb][1] = bv; acc[nb][2] = bv; acc[nb][3] = bv;
    }

    for (int c = 0; c < NCHK; c++) {
        if (c) __syncthreads();
#pragma unroll
        for (int i = 0; i < 4; i++) {
            int F = tid + i * 256;
            int row = F >> 4, j = F & 15;
            int jor = j ^ (row & 7);
            int n = n0 + row; if (n > NN - 1) n = NN - 1;
            const float* src;
            if (CIN == 64) {
                src = (c == 0 ? h_in + (size_t)n * 64
                              : agg + ((size_t)(c - 1) * NN + n) * 64) + jor * 4;
            } else {
                int sidx = 2 * c + (jor >> 3);
                int jj = jor & 7;
                src = (sidx == 0 ? h_in + (size_t)n * 32
                                 : agg + ((size_t)(sidx - 1) * NN + n) * 32) + jj * 4;
            }
            async_copy16(sIN + (size_t)F * 4, src);
        }
#pragma unroll
        for (int i = 0; i < 2; i++) {
            int F = tid + i * 256;
            int col = F >> 3, s = F & 7;
            int sor = s ^ (col & 7);
            const __bf16* sh = wh + (size_t)col * KT + c * 64 + sor * 8;
            const __bf16* sl = wl + (size_t)col * KT + c * 64 + sor * 8;
            async_copy16(sWH + (size_t)F * 8, sh);
            async_copy16(sWL + (size_t)F * 8, sl);
        }
        __syncthreads();
#pragma unroll
        for (int ks = 0; ks < 2; ks++) {
            const int rowL = wave * 16 + cA;
            const int jA = ks * 8 + kg * 2;
            float4 a0 = ((const float4*)sIN)[rowL * 16 + (jA ^ (rowL & 7))];
            float4 a1 = ((const float4*)sIN)[rowL * 16 + ((jA + 1) ^ (rowL & 7))];
            bf16x8 ah, al;
            split8(a0, a1, ah, al);
            const int k8 = ks * 4 + kg;
#pragma unroll
            for (int nb = 0; nb < 4; nb++) {
                const int col = nb * 16 + cA;
                const int bs = col * 8 + (k8 ^ (col & 7));
                bf16x8 bh = ((const bf16x8*)sWH)[bs];
                bf16x8 bl = ((const bf16x8*)sWL)[bs];
                acc[nb] = __builtin_amdgcn_mfma_f32_16x16x32_bf16(ah, bh, acc[nb], 0, 0, 0);
                acc[nb] = __builtin_amdgcn_mfma_f32_16x16x32_bf16(al, bh, acc[nb], 0, 0, 0);
                acc[nb] = __builtin_amdgcn_mfma_f32_16x16x32_bf16(ah, bl, acc[nb], 0, 0, 0);
                acc[nb] = __builtin_amdgcn_mfma_f32_16x16x32_bf16(al, bl, acc[nb], 0, 0, 0);
            }
        }
    }
#pragma unroll
    for (int nb = 0; nb < 4; nb++) {
#pragma unroll
        for (int r = 0; r < 4; r++) {
            int n = n0 + wave * 16 + kg * 4 + r;
            if (n < NN)
                h_out[(size_t)n * 64 + nb * 16 + cA] = fmaxf(acc[nb][r], 0.f);
        }
    }
}

// ---- mean pool via binary search on sorted batch (no atomics)
__global__ __launch_bounds__(256)
void k_pool(const float* __restrict__ h, const int* __restrict__ batch,
            float* __restrict__ pool) {
    int g = blockIdx.x;
    auto lb = [&](int v) {
        int lo = 0, hi = NN;
        while (lo < hi) {
            int m = (lo + hi) >> 1;
            if (batch[m] < v) lo = m + 1; else hi = m;
        }
        return lo;
    };
    int st = lb(g), en = lb(g + 1);
    int col = threadIdx.x & 63, chunk = threadIdx.x >> 6;
    float acc = 0.f;
    for (int n = st + chunk; n < en; n += 4) acc += h[(size_t)n * 64 + col];
    __shared__ float s[256];
    s[threadIdx.x] = acc;
    __syncthreads();
    if (chunk == 0) {
        float tot = s[col] + s[64 + col] + s[128 + col] + s[192 + col];
        int c = en - st;
        pool[g * 64 + col] = tot / (float)(c > 1 ? c : 1);
    }
}

// ---- classifier
__global__ __launch_bounds__(256)
void k_final(const float* __restrict__ pool, const float* __restrict__ cw,
             const float* __restrict__ cb, float* __restrict__ out) {
    int t = blockIdx.x * blockDim.x + threadIdx.x;
    if (t >= NG * 10) return;
    int g = t / 10, j = t % 10;
    float acc = 0.f;
#pragma unroll
    for (int k = 0; k < 64; k++) acc += pool[g * 64 + k] * cw[k * 10 + j];
    out[t] = cb[j] + acc;
}

extern "C" void kernel_launch(void* const* d_in, const int* in_sizes, int n_in,
                              void* d_out, int out_size, void* d_ws, size_t ws_size,
                              hipStream_t stream) {
    const int* x      = (const int*)d_in[0];
    const int* ei     = (const int*)d_in[1];
    const int* et     = (const int*)d_in[2];
    const int* batch  = (const int*)d_in[3];
    const float* se   = (const float*)d_in[4];
    const float* ce   = (const float*)d_in[5];
    const float* pw   = (const float*)d_in[6];
    const float* pb   = (const float*)d_in[7];
    const float* w1   = (const float*)d_in[8];
    const float* root1= (const float*)d_in[9];
    const float* b1   = (const float*)d_in[10];
    const float* w2   = (const float*)d_in[11];
    const float* root2= (const float*)d_in[12];
    const float* b2   = (const float*)d_in[13];
    const float* cw   = (const float*)d_in[14];
    const float* cbias= (const float*)d_in[15];
    float* out = (float*)d_out;

    char* ws = (char*)d_ws;
    float* agg   = (float*)(ws + AGG_OFF);
    int*   cur   = (int*)(ws + CUR_OFF);
    int*   start = (int*)(ws + START_OFF);
    int*   csum  = (int*)(ws + CSUM_OFF);
    int*   esrc  = (int*)(ws + ESRC_OFF);
    float* pool  = (float*)(ws + POOL_OFF);
    float* h0    = (float*)(ws + H0_OFF);
    float* h1    = (float*)(ws + H1_OFF);
    float* h2    = (float*)(ws + H2_OFF);
    __bf16* wt1h = (__bf16*)(ws + WT1H_OFF);
    __bf16* wt1l = (__bf16*)(ws + WT1L_OFF);
    __bf16* wt2h = (__bf16*)(ws + WT2H_OFF);
    __bf16* wt2l = (__bf16*)(ws + WT2L_OFF);
    float* table = (float*)(ws + TAB_OFF);
    unsigned char* cbarr = (unsigned char*)(ws + CB_OFF);

    // zero the histogram only
    hipMemsetAsync(cur, 0, (size_t)NSEG * 4, stream);

    k_cbtable<<<1, 256, 0, stream>>>(se, ce, pw, pb, table);
    k_node_init<<<(NN + 255) / 256, 256, 0, stream>>>(x, table, cbarr, h0);
    k_prepw<<<(64 * 128 + 255) / 256, 256, 0, stream>>>(root1, w1, wt1h, wt1l, 32);
    k_prepw<<<(64 * 256 + 255) / 256, 256, 0, stream>>>(root2, w2, wt2h, wt2l, 64);

    // CSR build
    k_count<<<(NE / 4 + 255) / 256, 256, 0, stream>>>(ei, et, cur);
    k_chunksum<<<NCHUNK, 256, 0, stream>>>(cur, csum);
    k_chunkscan<<<1, 512, 0, stream>>>(csum);
    k_localscan<<<NCHUNK, 256, 0, stream>>>(cur, csum, start);
    k_fill<<<(NE / 4 + 255) / 256, 256, 0, stream>>>(ei, et, cbarr, cur, esrc);

    // layer 1
    k_gather_t<<<(NSEG * 8 + 255) / 256, 256, 0, stream>>>(start, cur, esrc, table, agg);
    k_combine_m<32><<<(NN + 63) / 64, 256, 0, stream>>>(h0, agg, wt1h, wt1l, b1, h1);

    // layer 2
    k_gather64<<<(NSEG * 16 + 255) / 256, 256, 0, stream>>>(start, cur, esrc, h1, agg);
    k_combine_m<64><<<(NN + 63) / 64, 256, 0, stream>>>(h1, agg, wt2h, wt2l, b2, h2);

    // pooling + classifier
    k_pool<<<NG, 256, 0, stream>>>(h2, batch, pool);
    k_final<<<(NG * 10 + 255) / 256, 256, 0, stream>>>(pool, cw, cbias, out);
}

// Round 9
// 245.794 us; speedup vs baseline: 1.2855x; 1.2855x over previous
//
#include <hip/hip_runtime.h>

#define NN 100000
#define NE 1200000
#define NG 512
#define NSEG (3 * NN)
#define CHUNK 1024
#define NCHUNK ((NSEG + CHUNK - 1) / CHUNK)

typedef __bf16 bf16x8 __attribute__((ext_vector_type(8)));
typedef float f32x4 __attribute__((ext_vector_type(4)));

// ---- workspace layout (bytes), all 16B-aligned ----
static constexpr size_t AGG_OFF   = 0;                                  // 3*NN*64 f32
static constexpr size_t AGG_BYTES = (size_t)NSEG * 64 * 4;              // 76,800,000
static constexpr size_t HIST_OFF  = AGG_OFF + AGG_BYTES;                // NSEG ints (hist -> end)
static constexpr size_t START_OFF = HIST_OFF + (size_t)NSEG * 4;        // NSEG ints
static constexpr size_t CSUM_OFF  = START_OFF + (size_t)NSEG * 4;       // NCHUNK ints
static constexpr size_t ESRC_OFF  = CSUM_OFF + 4096;                    // NE ints (packed src|cb<<17)
static constexpr size_t POOL_OFF  = ESRC_OFF + (size_t)NE * 4;          // NG*64 f32
static constexpr size_t H0_OFF    = POOL_OFF + (size_t)NG * 64 * 4;     // NN*32 f32
static constexpr size_t H1_OFF    = H0_OFF + (size_t)NN * 32 * 4;       // NN*64 f32
static constexpr size_t H2_OFF    = H1_OFF + (size_t)NN * 64 * 4;       // NN*64 f32
static constexpr size_t WT1H_OFF  = H2_OFF + (size_t)NN * 64 * 4;       // 64*128 bf16
static constexpr size_t WT1L_OFF  = WT1H_OFF + 64 * 128 * 2;
static constexpr size_t WT2H_OFF  = WT1L_OFF + 64 * 128 * 2;            // 64*256 bf16
static constexpr size_t WT2L_OFF  = WT2H_OFF + 64 * 256 * 2;
static constexpr size_t TAB_OFF   = WT2L_OFF + 64 * 256 * 2;            // 256*32 f32 (32KB)
static constexpr size_t CB_OFF    = TAB_OFF + 256 * 32 * 4;             // NN bytes
static constexpr size_t RS_OFF    = ((CB_OFF + NN + 15) / 16) * 16;     // NE ints (rank<<19|seg)

// async global->LDS, 16B per lane; LDS dest = wave-uniform base + lane*16
__device__ __forceinline__ void async_copy16(void* lds, const void* g) {
    __builtin_amdgcn_global_load_lds(
        (const __attribute__((address_space(1))) void*)g,
        (__attribute__((address_space(3))) void*)lds, 16, 0, 0);
}

// ---- combo table: table[combo][32] = relu(concat(se[s],ce[c]) @ pre_w + pre_b)
__global__ __launch_bounds__(256)
void k_cbtable(const float* __restrict__ se, const float* __restrict__ ce,
               const float* __restrict__ pw, const float* __restrict__ pb,
               float* __restrict__ table) {
    __shared__ float sW[16 * 32];
    __shared__ float sB[32];
    for (int i = threadIdx.x; i < 512; i += 256) sW[i] = pw[i];
    if (threadIdx.x < 32) sB[threadIdx.x] = pb[threadIdx.x];
    __syncthreads();
    int cmb = threadIdx.x;            // 0..255
    int s = cmb >> 4, c = cmb & 15;
    float in[16];
#pragma unroll
    for (int k = 0; k < 8; k++) in[k] = se[s * 8 + k];
#pragma unroll
    for (int k = 0; k < 8; k++) in[8 + k] = ce[c * 8 + k];
    float acc[32];
#pragma unroll
    for (int j = 0; j < 32; j++) acc[j] = sB[j];
#pragma unroll
    for (int k = 0; k < 16; k++) {
        float hv = in[k];
#pragma unroll
        for (int j = 0; j < 32; j++) acc[j] += hv * sW[k * 32 + j];
    }
    float* o = table + (size_t)cmb * 32;
#pragma unroll
    for (int j = 0; j < 32; j += 4)
        *(float4*)(o + j) = make_float4(fmaxf(acc[j], 0.f), fmaxf(acc[j + 1], 0.f),
                                        fmaxf(acc[j + 2], 0.f), fmaxf(acc[j + 3], 0.f));
}

// ---- per-node init: cb[n] = combo id; h0[n][32] = table[cb[n]]
__global__ __launch_bounds__(256)
void k_node_init(const int* __restrict__ x, const float* __restrict__ table,
                 unsigned char* __restrict__ cb, float* __restrict__ h0) {
    int n = blockIdx.x * 256 + threadIdx.x;
    if (n >= NN) return;
    int si = x[2 * n], ci = x[2 * n + 1];
    int cmb = si * 16 + ci;
    cb[n] = (unsigned char)cmb;
    const float* t = table + (size_t)cmb * 32;
    float* o = h0 + (size_t)n * 32;
#pragma unroll
    for (int j = 0; j < 32; j += 4) *(float4*)(o + j) = *(const float4*)(t + j);
}

// ---- weight prep: Wt_hi/lo[j][k] (bf16, transposed, split) from [root | W_r] (fp32 [K][64])
__global__ __launch_bounds__(256)
void k_prepw(const float* __restrict__ root, const float* __restrict__ w,
             __bf16* __restrict__ wh, __bf16* __restrict__ wl, int cin) {
    int kt = 4 * cin;
    int t = blockIdx.x * 256 + threadIdx.x;
    if (t >= 64 * kt) return;
    int j = t / kt, k = t % kt;
    int sidx = k / cin, kk = k % cin;
    float v = (sidx == 0) ? root[kk * 64 + j]
                          : w[((size_t)(sidx - 1) * cin + kk) * 64 + j];
    __bf16 h = (__bf16)v;
    wh[t] = h;
    wl[t] = (__bf16)(v - (float)h);
}

// ---- phase A: per-(rel,dst) histogram + per-edge rank memo (dense write)
__global__ __launch_bounds__(256)
void k_rank(const int* __restrict__ ei, const int* __restrict__ et,
            int* __restrict__ hist, unsigned int* __restrict__ rs) {
    int e = blockIdx.x * 256 + threadIdx.x;
    if (e >= NE) return;
    int d = ei[NE + e];
    int r = et[e];
    int seg = r * NN + d;
    unsigned int rank = (unsigned int)atomicAdd(&hist[seg], 1);
    rs[e] = (rank << 19) | (unsigned int)seg;
}

// ---- scan pass 1: per-chunk sums
__global__ __launch_bounds__(256)
void k_chunksum(const int* __restrict__ hist, int* __restrict__ csum) {
    __shared__ int s[256];
    int b = blockIdx.x, t = threadIdx.x;
    int base = b * CHUNK + t * 4;
    int sum = 0;
#pragma unroll
    for (int k = 0; k < 4; k++) {
        int i = base + k;
        if (i < NSEG) sum += hist[i];
    }
    s[t] = sum;
    __syncthreads();
    for (int off = 128; off > 0; off >>= 1) {
        if (t < off) s[t] += s[t + off];
        __syncthreads();
    }
    if (t == 0) csum[b] = s[0];
}

// ---- scan pass 2: exclusive scan of chunk sums (one 512-thread block)
__global__ __launch_bounds__(512)
void k_chunkscan(int* __restrict__ csum) {
    __shared__ int s[512];
    int t = threadIdx.x;
    int v = (t < NCHUNK) ? csum[t] : 0;
    s[t] = v;
    __syncthreads();
    for (int off = 1; off < 512; off <<= 1) {
        int x = (t >= off) ? s[t - off] : 0;
        __syncthreads();
        s[t] += x;
        __syncthreads();
    }
    if (t < NCHUNK) csum[t] = s[t] - v;   // exclusive
}

// ---- scan pass 3: local exclusive scan; writes start[]; overwrites hist[] with end[]
__global__ __launch_bounds__(256)
void k_localscan(int* __restrict__ hist_end, const int* __restrict__ csum,
                 int* __restrict__ start) {
    __shared__ int s[256];
    int b = blockIdx.x, t = threadIdx.x;
    int base = b * CHUNK + t * 4;
    int v[4];
    int s4 = 0;
#pragma unroll
    for (int k = 0; k < 4; k++) {
        int i = base + k;
        v[k] = (i < NSEG) ? hist_end[i] : 0;
        s4 += v[k];
    }
    s[t] = s4;
    __syncthreads();
    for (int off = 1; off < 256; off <<= 1) {
        int x = (t >= off) ? s[t - off] : 0;
        __syncthreads();
        s[t] += x;
        __syncthreads();
    }
    int excl = s[t] - s4 + csum[b];
#pragma unroll
    for (int k = 0; k < 4; k++) {
        int i = base + k;
        if (i < NSEG) {
            start[i] = excl;
            hist_end[i] = excl + v[k];   // segment end
        }
        excl += v[k];
    }
}

// ---- phase B: atomic-free CSR scatter: esrc[start[seg]+rank] = src | cb[src]<<17
__global__ __launch_bounds__(256)
void k_fill2(const int* __restrict__ ei, const unsigned char* __restrict__ cb,
             const int* __restrict__ start, const unsigned int* __restrict__ rs,
             int* __restrict__ esrc) {
    int e = blockIdx.x * 256 + threadIdx.x;
    if (e >= NE) return;
    int s = ei[e];
    unsigned int v = rs[e];
    int seg = (int)(v & 0x7FFFFu);
    int pos = start[seg] + (int)(v >> 19);
    esrc[pos] = s | ((int)cb[s] << 17);
}

// ---- layer-1 gather from 256-row combo table (L1/L2-resident)
__global__ __launch_bounds__(256)
void k_gather_t(const int* __restrict__ start, const int* __restrict__ end,
                const int* __restrict__ esrc, const float* __restrict__ table,
                float* __restrict__ agg) {
    int tid = blockIdx.x * 256 + threadIdx.x;
    int seg = tid >> 3;
    int p = tid & 7;
    if (seg >= NSEG) return;
    int st = start[seg], en = end[seg];
    float4 acc = make_float4(0.f, 0.f, 0.f, 0.f);
    int i = st;
    for (; i + 4 <= en; i += 4) {
        int v0 = esrc[i], v1 = esrc[i + 1], v2 = esrc[i + 2], v3 = esrc[i + 3];
        float4 a = *(const float4*)(table + ((v0 >> 17) & 0xFF) * 32 + p * 4);
        float4 b = *(const float4*)(table + ((v1 >> 17) & 0xFF) * 32 + p * 4);
        float4 c = *(const float4*)(table + ((v2 >> 17) & 0xFF) * 32 + p * 4);
        float4 d = *(const float4*)(table + ((v3 >> 17) & 0xFF) * 32 + p * 4);
        acc.x += (a.x + b.x) + (c.x + d.x);
        acc.y += (a.y + b.y) + (c.y + d.y);
        acc.z += (a.z + b.z) + (c.z + d.z);
        acc.w += (a.w + b.w) + (c.w + d.w);
    }
    for (; i < en; i++) {
        int v = esrc[i];
        float4 a = *(const float4*)(table + ((v >> 17) & 0xFF) * 32 + p * 4);
        acc.x += a.x; acc.y += a.y; acc.z += a.z; acc.w += a.w;
    }
    int c = en - st;
    float inv = 1.f / (float)(c > 1 ? c : 1);
    acc.x *= inv; acc.y *= inv; acc.z *= inv; acc.w *= inv;
    *(float4*)(agg + (size_t)seg * 32 + p * 4) = acc;
}

// ---- layer-2 gather: agg[seg][0:64] = MEAN h[src][0:64]
__global__ __launch_bounds__(256)
void k_gather64(const int* __restrict__ start, const int* __restrict__ end,
                const int* __restrict__ esrc, const float* __restrict__ h,
                float* __restrict__ agg) {
    int tid = blockIdx.x * 256 + threadIdx.x;
    int seg = tid >> 4;
    int p = tid & 15;
    if (seg >= NSEG) return;
    int st = start[seg], en = end[seg];
    float4 acc = make_float4(0.f, 0.f, 0.f, 0.f);
    int i = st;
    for (; i + 4 <= en; i += 4) {
        int s0 = esrc[i] & 0x1FFFF, s1 = esrc[i + 1] & 0x1FFFF;
        int s2 = esrc[i + 2] & 0x1FFFF, s3 = esrc[i + 3] & 0x1FFFF;
        float4 v0 = *(const float4*)(h + (size_t)s0 * 64 + p * 4);
        float4 v1 = *(const float4*)(h + (size_t)s1 * 64 + p * 4);
        float4 v2 = *(const float4*)(h + (size_t)s2 * 64 + p * 4);
        float4 v3 = *(const float4*)(h + (size_t)s3 * 64 + p * 4);
        acc.x += (v0.x + v1.x) + (v2.x + v3.x);
        acc.y += (v0.y + v1.y) + (v2.y + v3.y);
        acc.z += (v0.z + v1.z) + (v2.z + v3.z);
        acc.w += (v0.w + v1.w) + (v2.w + v3.w);
    }
    for (; i < en; i++) {
        int s = esrc[i] & 0x1FFFF;
        float4 v = *(const float4*)(h + (size_t)s * 64 + p * 4);
        acc.x += v.x; acc.y += v.y; acc.z += v.z; acc.w += v.w;
    }
    int c = en - st;
    float inv = 1.f / (float)(c > 1 ? c : 1);
    acc.x *= inv; acc.y *= inv; acc.z *= inv; acc.w *= inv;
    *(float4*)(agg + (size_t)seg * 64 + p * 4) = acc;
}

// split 8 fp32 -> hi/lo bf16x8 fragments (hi+lo represents x to ~2^-18 rel)
__device__ __forceinline__ void split8(float4 a0, float4 a1, bf16x8& hi, bf16x8& lo) {
    float v[8] = {a0.x, a0.y, a0.z, a0.w, a1.x, a1.y, a1.z, a1.w};
#pragma unroll
    for (int i = 0; i < 8; i++) {
        __bf16 h = (__bf16)v[i];
        hi[i] = h;
        lo[i] = (__bf16)(v[i] - (float)h);
    }
}

// ---- combine via split-bf16 MFMA
template <int CIN>
__global__ __launch_bounds__(256, 1)
void k_combine_m(const float* __restrict__ h_in, const float* __restrict__ agg,
                 const __bf16* __restrict__ wh, const __bf16* __restrict__ wl,
                 const float* __restrict__ bias, float* __restrict__ h_out) {
    constexpr int KT = 4 * CIN;          // 128 or 256
    constexpr int NCHK = KT / 64;        // 2 or 4 chunks of K=64
    __shared__ float sIN[64 * 64];       // 16 KB
    __shared__ __bf16 sWH[64 * 64];      // 8 KB
    __shared__ __bf16 sWL[64 * 64];      // 8 KB

    const int tid = threadIdx.x;
    const int wave = tid >> 6;
    const int lane = tid & 63;
    const int cA = lane & 15;
    const int kg = lane >> 4;
    const int n0 = blockIdx.x * 64;

    f32x4 acc[4];
#pragma unroll
    for (int nb = 0; nb < 4; nb++) {
        float bv = bias[nb * 16 + cA];
        acc[nb][0] = bv; acc[nb][1] = bv; acc[nb][2] = bv; acc[nb][3] = bv;
    }

    for (int c = 0; c < NCHK; c++) {
        if (c) __syncthreads();
#pragma unroll
        for (int i = 0; i < 4; i++) {
            int F = tid + i * 256;
            int row = F >> 4, j = F & 15;
            int jor = j ^ (row & 7);
            int n = n0 + row; if (n > NN - 1) n = NN - 1;
            const float* src;
            if (CIN == 64) {
                src = (c == 0 ? h_in + (size_t)n * 64
                              : agg + ((size_t)(c - 1) * NN + n) * 64) + jor * 4;
            } else {
                int sidx = 2 * c + (jor >> 3);
                int jj = jor & 7;
                src = (sidx == 0 ? h_in + (size_t)n * 32
                                 : agg + ((size_t)(sidx - 1) * NN + n) * 32) + jj * 4;
            }
            async_copy16(sIN + (size_t)F * 4, src);
        }
#pragma unroll
        for (int i = 0; i < 2; i++) {
            int F = tid + i * 256;
            int col = F >> 3, s = F & 7;
            int sor = s ^ (col & 7);
            const __bf16* sh = wh + (size_t)col * KT + c * 64 + sor * 8;
            const __bf16* sl = wl + (size_t)col * KT + c * 64 + sor * 8;
            async_copy16(sWH + (size_t)F * 8, sh);
            async_copy16(sWL + (size_t)F * 8, sl);
        }
        __syncthreads();
#pragma unroll
        for (int ks = 0; ks < 2; ks++) {
            const int rowL = wave * 16 + cA;
            const int jA = ks * 8 + kg * 2;
            float4 a0 = ((const float4*)sIN)[rowL * 16 + (jA ^ (rowL & 7))];
            float4 a1 = ((const float4*)sIN)[rowL * 16 + ((jA + 1) ^ (rowL & 7))];
            bf16x8 ah, al;
            split8(a0, a1, ah, al);
            const int k8 = ks * 4 + kg;
#pragma unroll
            for (int nb = 0; nb < 4; nb++) {
                const int col = nb * 16 + cA;
                const int bs = col * 8 + (k8 ^ (col & 7));
                bf16x8 bh = ((const bf16x8*)sWH)[bs];
                bf16x8 bl = ((const bf16x8*)sWL)[bs];
                acc[nb] = __builtin_amdgcn_mfma_f32_16x16x32_bf16(ah, bh, acc[nb], 0, 0, 0);
                acc[nb] = __builtin_amdgcn_mfma_f32_16x16x32_bf16(al, bh, acc[nb], 0, 0, 0);
                acc[nb] = __builtin_amdgcn_mfma_f32_16x16x32_bf16(ah, bl, acc[nb], 0, 0, 0);
                acc[nb] = __builtin_amdgcn_mfma_f32_16x16x32_bf16(al, bl, acc[nb], 0, 0, 0);
            }
        }
    }
#pragma unroll
    for (int nb = 0; nb < 4; nb++) {
#pragma unroll
        for (int r = 0; r < 4; r++) {
            int n = n0 + wave * 16 + kg * 4 + r;
            if (n < NN)
                h_out[(size_t)n * 64 + nb * 16 + cA] = fmaxf(acc[nb][r], 0.f);
        }
    }
}

// ---- mean pool via binary search on sorted batch (no atomics)
__global__ __launch_bounds__(256)
void k_pool(const float* __restrict__ h, const int* __restrict__ batch,
            float* __restrict__ pool) {
    int g = blockIdx.x;
    auto lb = [&](int v) {
        int lo = 0, hi = NN;
        while (lo < hi) {
            int m = (lo + hi) >> 1;
            if (batch[m] < v) lo = m + 1; else hi = m;
        }
        return lo;
    };
    int st = lb(g), en = lb(g + 1);
    int col = threadIdx.x & 63, chunk = threadIdx.x >> 6;
    float acc = 0.f;
    for (int n = st + chunk; n < en; n += 4) acc += h[(size_t)n * 64 + col];
    __shared__ float s[256];
    s[threadIdx.x] = acc;
    __syncthreads();
    if (chunk == 0) {
        float tot = s[col] + s[64 + col] + s[128 + col] + s[192 + col];
        int c = en - st;
        pool[g * 64 + col] = tot / (float)(c > 1 ? c : 1);
    }
}

// ---- classifier
__global__ __launch_bounds__(256)
void k_final(const float* __restrict__ pool, const float* __restrict__ cw,
             const float* __restrict__ cb, float* __restrict__ out) {
    int t = blockIdx.x * blockDim.x + threadIdx.x;
    if (t >= NG * 10) return;
    int g = t / 10, j = t % 10;
    float acc = 0.f;
#pragma unroll
    for (int k = 0; k < 64; k++) acc += pool[g * 64 + k] * cw[k * 10 + j];
    out[t] = cb[j] + acc;
}

extern "C" void kernel_launch(void* const* d_in, const int* in_sizes, int n_in,
                              void* d_out, int out_size, void* d_ws, size_t ws_size,
                              hipStream_t stream) {
    const int* x      = (const int*)d_in[0];
    const int* ei     = (const int*)d_in[1];
    const int* et     = (const int*)d_in[2];
    const int* batch  = (const int*)d_in[3];
    const float* se   = (const float*)d_in[4];
    const float* ce   = (const float*)d_in[5];
    const float* pw   = (const float*)d_in[6];
    const float* pb   = (const float*)d_in[7];
    const float* w1   = (const float*)d_in[8];
    const float* root1= (const float*)d_in[9];
    const float* b1   = (const float*)d_in[10];
    const float* w2   = (const float*)d_in[11];
    const float* root2= (const float*)d_in[12];
    const float* b2   = (const float*)d_in[13];
    const float* cw   = (const float*)d_in[14];
    const float* cbias= (const float*)d_in[15];
    float* out = (float*)d_out;

    char* ws = (char*)d_ws;
    float* agg   = (float*)(ws + AGG_OFF);
    int*   hist  = (int*)(ws + HIST_OFF);    // histogram -> end[] after localscan
    int*   start = (int*)(ws + START_OFF);
    int*   csum  = (int*)(ws + CSUM_OFF);
    int*   esrc  = (int*)(ws + ESRC_OFF);
    float* pool  = (float*)(ws + POOL_OFF);
    float* h0    = (float*)(ws + H0_OFF);
    float* h1    = (float*)(ws + H1_OFF);
    float* h2    = (float*)(ws + H2_OFF);
    __bf16* wt1h = (__bf16*)(ws + WT1H_OFF);
    __bf16* wt1l = (__bf16*)(ws + WT1L_OFF);
    __bf16* wt2h = (__bf16*)(ws + WT2H_OFF);
    __bf16* wt2l = (__bf16*)(ws + WT2L_OFF);
    float* table = (float*)(ws + TAB_OFF);
    unsigned char* cbarr = (unsigned char*)(ws + CB_OFF);
    unsigned int* rs = (unsigned int*)(ws + RS_OFF);

    // zero the histogram only
    hipMemsetAsync(hist, 0, (size_t)NSEG * 4, stream);

    k_cbtable<<<1, 256, 0, stream>>>(se, ce, pw, pb, table);
    k_node_init<<<(NN + 255) / 256, 256, 0, stream>>>(x, table, cbarr, h0);
    k_prepw<<<(64 * 128 + 255) / 256, 256, 0, stream>>>(root1, w1, wt1h, wt1l, 32);
    k_prepw<<<(64 * 256 + 255) / 256, 256, 0, stream>>>(root2, w2, wt2h, wt2l, 64);

    // CSR build (phase A: rank + hist; scan; phase B: atomic-free scatter)
    k_rank<<<(NE + 255) / 256, 256, 0, stream>>>(ei, et, hist, rs);
    k_chunksum<<<NCHUNK, 256, 0, stream>>>(hist, csum);
    k_chunkscan<<<1, 512, 0, stream>>>(csum);
    k_localscan<<<NCHUNK, 256, 0, stream>>>(hist, csum, start);
    k_fill2<<<(NE + 255) / 256, 256, 0, stream>>>(ei, cbarr, start, rs, esrc);

    // layer 1
    k_gather_t<<<(NSEG * 8 + 255) / 256, 256, 0, stream>>>(start, hist, esrc, table, agg);
    k_combine_m<32><<<(NN + 63) / 64, 256, 0, stream>>>(h0, agg, wt1h, wt1l, b1, h1);

    // layer 2
    k_gather64<<<(NSEG * 16 + 255) / 256, 256, 0, stream>>>(start, hist, esrc, h1, agg);
    k_combine_m<64><<<(NN + 63) / 64, 256, 0, stream>>>(h1, agg, wt2h, wt2l, b2, h2);

    // pooling + classifier
    k_pool<<<NG, 256, 0, stream>>>(h2, batch, pool);
    k_final<<<(NG * 10 + 255) / 256, 256, 0, stream>>>(pool, cw, cbias, out);
}